// Round 1
// baseline (189.881 us; speedup 1.0000x reference)
//
#include <hip/hip_runtime.h>

typedef __attribute__((ext_vector_type(8))) short bf16x8;
typedef __attribute__((ext_vector_type(4))) float f32x4;

#define B_SZ   64
#define CIN    256
#define COUT   256
#define CS     256
#define HIDDEN 64
#define L_SZ   1024
#define LPAD   1026   // l index padded by 1 on each side
#define TEMP   30.0f

// workspace offsets (bytes), all 256-aligned
#define OFF_ATT   0u          // 64*4 floats          = 1 KB
#define OFF_AGGB  1024u       // 64*256 floats        = 64 KB
#define OFF_WAGG  66560u      // 64*3*256*256 bf16    = 25165824 B
#define OFF_XBF   25232384u   // 64*1026*256 bf16     = 33619968 B
// total ~56.2 MB

__device__ __forceinline__ unsigned short f2bf(float f) {
    union { float f; unsigned int u; } v; v.f = f;
    unsigned int u = v.u;
    return (unsigned short)((u + 0x7fffu + ((u >> 16) & 1u)) >> 16);
}

__device__ __forceinline__ void load_lds16(const unsigned short* g, unsigned short* l) {
    __builtin_amdgcn_global_load_lds(
        (const __attribute__((address_space(1))) unsigned int*)g,
        (__attribute__((address_space(3))) unsigned int*)l, 16, 0, 0);
}

// ---------------------------------------------------------------------------
// Kernel 1: routing MLP -> att (B,4), agg_b (B,256); also zero xbf pad rows.
// grid = 64 (b), block = 256
// ---------------------------------------------------------------------------
__global__ void routing_kernel(const float* __restrict__ cond,
                               const float* __restrict__ w1,
                               const float* __restrict__ w2,
                               const float* __restrict__ bias,
                               float* __restrict__ att_g,
                               float* __restrict__ aggb_g,
                               unsigned short* __restrict__ xbf) {
    __shared__ float cond_s[CS];
    __shared__ float h_s[HIDDEN];
    __shared__ float lg_s[4];
    int t = threadIdx.x;
    int b = blockIdx.x;
    cond_s[t] = cond[b * CS + t];
    // zero the padded rows (l = -1 and l = 1024) of xbf for this b
    xbf[(size_t)b * LPAD * CIN + t] = 0;
    xbf[((size_t)b * LPAD + (LPAD - 1)) * CIN + t] = 0;
    __syncthreads();
    // h = relu(cond @ w1^T): 64 outputs, 4 lanes each
    int jj = t >> 2, s = t & 3;
    float p = 0.f;
    const float* w1r = w1 + jj * CS + s * 64;
    const float* cs  = cond_s + s * 64;
    #pragma unroll 16
    for (int c = 0; c < 64; ++c) p += cs[c] * w1r[c];
    p += __shfl_down(p, 2, 4);
    p += __shfl_down(p, 1, 4);
    if (s == 0) h_s[jj] = fmaxf(p, 0.f);
    __syncthreads();
    if (t < 4) {
        float z = 0.f;
        #pragma unroll 16
        for (int h = 0; h < HIDDEN; ++h) z += h_s[h] * w2[t * HIDDEN + h];
        lg_s[t] = z * (1.0f / TEMP);
    }
    __syncthreads();
    float l0 = lg_s[0], l1 = lg_s[1], l2 = lg_s[2], l3 = lg_s[3];
    float mx = fmaxf(fmaxf(l0, l1), fmaxf(l2, l3));
    float e0 = __expf(l0 - mx), e1 = __expf(l1 - mx);
    float e2 = __expf(l2 - mx), e3 = __expf(l3 - mx);
    float inv = 1.0f / (e0 + e1 + e2 + e3);
    float a0 = e0 * inv, a1 = e1 * inv, a2 = e2 * inv, a3 = e3 * inv;
    if (t == 0) {
        att_g[b * 4 + 0] = a0; att_g[b * 4 + 1] = a1;
        att_g[b * 4 + 2] = a2; att_g[b * 4 + 3] = a3;
    }
    aggb_g[b * COUT + t] = a0 * bias[0 * COUT + t] + a1 * bias[1 * COUT + t]
                         + a2 * bias[2 * COUT + t] + a3 * bias[3 * COUT + t];
}

// ---------------------------------------------------------------------------
// Kernel 2: x (B,CIN,L) fp32 -> xbf (B, LPAD, CIN) bf16  (transpose + cast)
// grid = (16 l-tiles, 4 i-tiles, 64 b), block = 256
// ---------------------------------------------------------------------------
__global__ void xpose_kernel(const float* __restrict__ x,
                             unsigned short* __restrict__ xbf) {
    __shared__ float tile[64][65];
    int lt = blockIdx.x, it = blockIdx.y, b = blockIdx.z;
    int t = threadIdx.x;
    int w = t >> 6, lane = t & 63;
    const float* xp = x + ((size_t)b * CIN + it * 64) * L_SZ + lt * 64;
    #pragma unroll
    for (int rr = 0; rr < 16; ++rr) {
        int i_loc = rr * 4 + w;
        tile[i_loc][lane] = xp[(size_t)i_loc * L_SZ + lane];
    }
    __syncthreads();
    #pragma unroll
    for (int ww = 0; ww < 16; ++ww) {
        int l_loc = ww * 4 + w;
        xbf[((size_t)b * LPAD + lt * 64 + l_loc + 1) * CIN + it * 64 + lane] =
            f2bf(tile[lane][l_loc]);
    }
}

// ---------------------------------------------------------------------------
// Kernel 3: W_agg[b][kh][o][i] = sum_k att[b][k] * weight[k][o][i][kh][1] (bf16)
// grid = (256 o, 4 b-chunks), block = 256 (i)
// ---------------------------------------------------------------------------
__global__ void wagg_kernel(const float* __restrict__ weight,
                            const float* __restrict__ att_g,
                            unsigned short* __restrict__ wagg) {
    int o = blockIdx.x, bc = blockIdx.y, i = threadIdx.x;
    float wr[3][4];
    #pragma unroll
    for (int k = 0; k < 4; ++k) {
        const float* wp = weight + (((size_t)k * COUT + o) * CIN + i) * 9 + 1;
        #pragma unroll
        for (int kh = 0; kh < 3; ++kh) wr[kh][k] = wp[kh * 3];
    }
    #pragma unroll
    for (int bb = 0; bb < 16; ++bb) {
        int b = bc * 16 + bb;
        float a0 = att_g[b * 4 + 0], a1 = att_g[b * 4 + 1];
        float a2 = att_g[b * 4 + 2], a3 = att_g[b * 4 + 3];
        #pragma unroll
        for (int kh = 0; kh < 3; ++kh) {
            float v = wr[kh][0] * a0 + wr[kh][1] * a1 + wr[kh][2] * a2 + wr[kh][3] * a3;
            wagg[(((size_t)b * 3 + kh) * COUT + o) * CIN + i] = f2bf(v);
        }
    }
}

// ---------------------------------------------------------------------------
// Kernel 4: per-sample GEMM  Y[b] = sum_kh Wagg[b][kh] (256x256) @ Xshift (256x1024)
// 128x128 tile, BK=32, 3 kh passes per staged tile. 4 waves, each 64x64.
// grid = 1024 (8 n-tiles x 2 m-tiles x 64 b), block = 256
// ---------------------------------------------------------------------------
__global__ __launch_bounds__(256)
void dynconv_gemm(const unsigned short* __restrict__ wagg,
                  const unsigned short* __restrict__ xbf,
                  const float* __restrict__ aggb,
                  float* __restrict__ out) {
    __shared__ unsigned short As[3 * 128 * 32];  // 24576 B: [kh][m][k]
    __shared__ unsigned short Bs[144 * 32];      //  9216 B: [l_local][k] (130 used)
    int bx = blockIdx.x;
    int nt = bx & 7, mt = (bx >> 3) & 1, b = bx >> 4;
    int l0 = nt * 128, m0 = mt * 128;
    int t = threadIdx.x;
    int w = t >> 6, lane = t & 63;
    int ln = lane & 15, hi = lane >> 4;
    int wm = w & 1, wn = w >> 1;
    int jq = lane >> 2, jc = lane & 3;

    f32x4 acc[4][4];
    #pragma unroll
    for (int a = 0; a < 4; ++a)
        #pragma unroll
        for (int c = 0; c < 4; ++c) acc[a][c] = (f32x4){0.f, 0.f, 0.f, 0.f};

    const unsigned short* wb = wagg + (size_t)b * 3 * COUT * CIN;
    const unsigned short* xb = xbf + (size_t)b * LPAD * CIN;

    for (int it = 0; it < 8; ++it) {
        int i0 = it * 32;
        // A staging: 384 rows of 64 B (3 kh x 128 m); 16 rows/instr; 6 instr/wave
        #pragma unroll
        for (int s = 0; s < 6; ++s) {
            int inst = w * 6 + s;
            int R = inst * 16 + jq;           // 0..383
            int kh = R >> 7, m = R & 127;
            const unsigned short* g =
                wb + ((size_t)(kh * COUT + m0 + m)) * CIN + i0 + jc * 8;
            load_lds16(g, &As[inst * 512]);
        }
        // B staging: 130 rows needed (l0-1 .. l0+128 in padded coords = l0..l0+129)
        for (int bi = w; bi < 9; bi += 4) {
            int r = bi * 16 + jq;             // 0..143 (rows >=130 unused)
            int grow = min(l0 + r, LPAD - 1); // clamp overread into valid memory
            const unsigned short* g = xb + (size_t)grow * CIN + i0 + jc * 8;
            load_lds16(g, &Bs[bi * 512]);
        }
        __syncthreads();
        #pragma unroll
        for (int kh = 0; kh < 3; ++kh) {
            bf16x8 af[4], bfr[4];
            #pragma unroll
            for (int mi = 0; mi < 4; ++mi)
                af[mi] = *(const bf16x8*)&As[kh * 4096 + (wm * 64 + mi * 16 + ln) * 32 + hi * 8];
            #pragma unroll
            for (int ni = 0; ni < 4; ++ni)
                bfr[ni] = *(const bf16x8*)&Bs[(wn * 64 + ni * 16 + ln + kh) * 32 + hi * 8];
            #pragma unroll
            for (int mi = 0; mi < 4; ++mi)
                #pragma unroll
                for (int ni = 0; ni < 4; ++ni)
                    acc[mi][ni] = __builtin_amdgcn_mfma_f32_16x16x32_bf16(
                        af[mi], bfr[ni], acc[mi][ni], 0, 0, 0);
        }
        __syncthreads();
    }

    // epilogue: C/D layout col=lane&15 (=l), row=(lane>>4)*4+reg (=o); add bias
    const float* abb = aggb + b * COUT;
    float* ob = out + (size_t)b * COUT * L_SZ;
    #pragma unroll
    for (int mi = 0; mi < 4; ++mi) {
        #pragma unroll
        for (int reg = 0; reg < 4; ++reg) {
            int o = m0 + wm * 64 + mi * 16 + hi * 4 + reg;
            float bv = abb[o];
            #pragma unroll
            for (int ni = 0; ni < 4; ++ni) {
                int l = l0 + wn * 64 + ni * 16 + ln;
                ob[(size_t)o * L_SZ + l] = acc[mi][ni][reg] + bv;
            }
        }
    }
}

extern "C" void kernel_launch(void* const* d_in, const int* in_sizes, int n_in,
                              void* d_out, int out_size, void* d_ws, size_t ws_size,
                              hipStream_t stream) {
    const float* x      = (const float*)d_in[0];
    const float* cond   = (const float*)d_in[1];
    const float* w1     = (const float*)d_in[2];
    const float* w2     = (const float*)d_in[3];
    const float* weight = (const float*)d_in[4];
    const float* bias   = (const float*)d_in[5];
    float* out = (float*)d_out;
    char* ws = (char*)d_ws;
    float* att_g  = (float*)(ws + OFF_ATT);
    float* aggb_g = (float*)(ws + OFF_AGGB);
    unsigned short* wagg = (unsigned short*)(ws + OFF_WAGG);
    unsigned short* xbf  = (unsigned short*)(ws + OFF_XBF);

    routing_kernel<<<64, 256, 0, stream>>>(cond, w1, w2, bias, att_g, aggb_g, xbf);
    xpose_kernel<<<dim3(16, 4, 64), 256, 0, stream>>>(x, xbf);
    wagg_kernel<<<dim3(256, 4), 256, 0, stream>>>(weight, att_g, wagg);
    dynconv_gemm<<<1024, 256, 0, stream>>>(wagg, xbf, aggb_g, out);
}

// Round 2
// 175.208 us; speedup vs baseline: 1.0837x; 1.0837x over previous
//
#include <hip/hip_runtime.h>

typedef __attribute__((ext_vector_type(8))) short bf16x8;
typedef __attribute__((ext_vector_type(4))) short s16x4;
typedef __attribute__((ext_vector_type(4))) float f32x4;

#define B_SZ   64
#define CIN    256
#define COUT   256
#define CS     256
#define HIDDEN 64
#define L_SZ   1024
#define LPAD   1026   // l index padded by 1 on each side
#define TEMP   30.0f

// workspace offsets (bytes), all 256-aligned
#define OFF_ATT   0u          // 64*4 floats          = 1 KB
#define OFF_AGGB  1024u       // 64*256 floats        = 64 KB
#define OFF_WAGG  66560u      // 64*3*256*256 bf16    = 25165824 B
#define OFF_XBF   25232384u   // 64*1026*256 bf16     = 33619968 B

__device__ __forceinline__ unsigned short f2bf(float f) {
    union { float f; unsigned int u; } v; v.f = f;
    unsigned int u = v.u;
    return (unsigned short)((u + 0x7fffu + ((u >> 16) & 1u)) >> 16);
}

__device__ __forceinline__ void load_lds16(const unsigned short* g, unsigned short* l) {
    __builtin_amdgcn_global_load_lds(
        (const __attribute__((address_space(1))) unsigned int*)g,
        (__attribute__((address_space(3))) unsigned int*)l, 16, 0, 0);
}

// ---------------------------------------------------------------------------
// Kernel 1: routing MLP -> att (B,4), agg_b (B,256); also zero xbf pad rows.
// ---------------------------------------------------------------------------
__global__ void routing_kernel(const float* __restrict__ cond,
                               const float* __restrict__ w1,
                               const float* __restrict__ w2,
                               const float* __restrict__ bias,
                               float* __restrict__ att_g,
                               float* __restrict__ aggb_g,
                               unsigned short* __restrict__ xbf) {
    __shared__ float cond_s[CS];
    __shared__ float h_s[HIDDEN];
    __shared__ float lg_s[4];
    int t = threadIdx.x;
    int b = blockIdx.x;
    cond_s[t] = cond[b * CS + t];
    xbf[(size_t)b * LPAD * CIN + t] = 0;
    xbf[((size_t)b * LPAD + (LPAD - 1)) * CIN + t] = 0;
    __syncthreads();
    int jj = t >> 2, s = t & 3;
    float p = 0.f;
    const float* w1r = w1 + jj * CS + s * 64;
    const float* cs  = cond_s + s * 64;
    #pragma unroll 16
    for (int c = 0; c < 64; ++c) p += cs[c] * w1r[c];
    p += __shfl_down(p, 2, 4);
    p += __shfl_down(p, 1, 4);
    if (s == 0) h_s[jj] = fmaxf(p, 0.f);
    __syncthreads();
    if (t < 4) {
        float z = 0.f;
        #pragma unroll 16
        for (int h = 0; h < HIDDEN; ++h) z += h_s[h] * w2[t * HIDDEN + h];
        lg_s[t] = z * (1.0f / TEMP);
    }
    __syncthreads();
    float l0 = lg_s[0], l1 = lg_s[1], l2 = lg_s[2], l3 = lg_s[3];
    float mx = fmaxf(fmaxf(l0, l1), fmaxf(l2, l3));
    float e0 = __expf(l0 - mx), e1 = __expf(l1 - mx);
    float e2 = __expf(l2 - mx), e3 = __expf(l3 - mx);
    float inv = 1.0f / (e0 + e1 + e2 + e3);
    float a0 = e0 * inv, a1 = e1 * inv, a2 = e2 * inv, a3 = e3 * inv;
    if (t == 0) {
        att_g[b * 4 + 0] = a0; att_g[b * 4 + 1] = a1;
        att_g[b * 4 + 2] = a2; att_g[b * 4 + 3] = a3;
    }
    aggb_g[b * COUT + t] = a0 * bias[0 * COUT + t] + a1 * bias[1 * COUT + t]
                         + a2 * bias[2 * COUT + t] + a3 * bias[3 * COUT + t];
}

// ---------------------------------------------------------------------------
// Kernel 2: x (B,CIN,L) fp32 -> xbf (B,LPAD,CIN) bf16. float4 reads,
// in-register 4x4 shuffle transpose (xor 16/32), vector LDS, b128 stores.
// grid = (16 l-tiles, 4 i-tiles, 64 b), block = 256
// ---------------------------------------------------------------------------
__global__ void xpose_kernel(const float* __restrict__ x,
                             unsigned short* __restrict__ xbf) {
    __shared__ unsigned short tileB[64 * 68];  // [l][i], stride 68 shorts
    int lt = blockIdx.x, it = blockIdx.y, b = blockIdx.z;
    int t = threadIdx.x;
    int w = t >> 6, lane = t & 63;
    int sub = lane & 15, grp = lane >> 4;

    const float4* xp4 = (const float4*)x;
    // base float4 index for (b, i-row, l-col)
    #pragma unroll
    for (int j = 0; j < 4; ++j) {
        int i_loc = w * 16 + j * 4 + grp;
        float4 v = xp4[((size_t)(b * CIN + it * 64 + i_loc)) * (L_SZ / 4)
                       + lt * 16 + sub];
        // 4x4 transpose across lanes {sub, sub+16, sub+32, sub+48}
        {   // step 1: xor 16 (grp bit0)
            float a = (grp & 1) ? v.x : v.y;
            float c = (grp & 1) ? v.z : v.w;
            float ra = __shfl_xor(a, 16);
            float rc = __shfl_xor(c, 16);
            if (grp & 1) { v.x = ra; v.z = rc; } else { v.y = ra; v.w = rc; }
        }
        {   // step 2: xor 32 (grp bit1)
            float a  = (grp & 2) ? v.x : v.z;
            float b2 = (grp & 2) ? v.y : v.w;
            float ra = __shfl_xor(a, 32);
            float rb = __shfl_xor(b2, 32);
            if (grp & 2) { v.x = ra; v.y = rb; } else { v.z = ra; v.w = rb; }
        }
        // lane now holds i = w*16+j*4+{0..3} at l = lt*64 + sub*4 + grp
        int l_loc = sub * 4 + grp;
        s16x4 pk;
        pk.x = (short)f2bf(v.x); pk.y = (short)f2bf(v.y);
        pk.z = (short)f2bf(v.z); pk.w = (short)f2bf(v.w);
        *(s16x4*)&tileB[l_loc * 68 + w * 16 + j * 4] = pk;
    }
    __syncthreads();
    // write out: rows l_loc, 64 i contiguous (128 B) per row
    int row = t >> 2, c0 = t & 3;
    unsigned short* dst = xbf + ((size_t)b * LPAD + lt * 64 + row + 1) * CIN + it * 64;
    #pragma unroll
    for (int h = 0; h < 2; ++h) {
        int c = c0 + h * 4;
        bf16x8 vv = *(const bf16x8*)&tileB[row * 68 + c * 8];
        *(bf16x8*)&dst[c * 8] = vv;
    }
}

// ---------------------------------------------------------------------------
// Kernel 3: W_agg[b][kh][o][i] = sum_k att[b][k] * weight[k][o][i][kh][1]
// One block per (o, b-chunk of 32). Weight staged coalesced via float4.
// ---------------------------------------------------------------------------
__global__ void wagg_kernel(const float* __restrict__ weight,
                            const float* __restrict__ att_g,
                            unsigned short* __restrict__ wagg) {
    __shared__ float w_s[4][2304];
    __shared__ float att_s[128];
    int o = blockIdx.x, bc = blockIdx.y;
    int t = threadIdx.x;
    if (t < 128) att_s[t] = att_g[bc * 128 + t];
    #pragma unroll
    for (int k = 0; k < 4; ++k) {
        const float4* src = (const float4*)(weight + ((size_t)k * COUT + o) * 2304);
        for (int idx = t; idx < 576; idx += 256)
            *(float4*)&w_s[k][idx * 4] = src[idx];
    }
    __syncthreads();
    int i = t;
    float wv[3][4];
    #pragma unroll
    for (int kh = 0; kh < 3; ++kh)
        #pragma unroll
        for (int k = 0; k < 4; ++k)
            wv[kh][k] = w_s[k][i * 9 + kh * 3 + 1];
    for (int bb = 0; bb < 32; ++bb) {
        int b = bc * 32 + bb;
        float a0 = att_s[bb * 4 + 0], a1 = att_s[bb * 4 + 1];
        float a2 = att_s[bb * 4 + 2], a3 = att_s[bb * 4 + 3];
        #pragma unroll
        for (int kh = 0; kh < 3; ++kh) {
            float v = wv[kh][0] * a0 + wv[kh][1] * a1 + wv[kh][2] * a2 + wv[kh][3] * a3;
            wagg[(((size_t)b * 3 + kh) * COUT + o) * CIN + i] = f2bf(v);
        }
    }
}

// ---------------------------------------------------------------------------
// Kernel 4: per-sample GEMM with XCD-locality block swizzle + LDS chunk-XOR
// swizzle. 128x128 tile, BK=32, 3 kh passes. grid = 1024, block = 256.
// ---------------------------------------------------------------------------
__global__ __launch_bounds__(256)
void dynconv_gemm(const unsigned short* __restrict__ wagg,
                  const unsigned short* __restrict__ xbf,
                  const float* __restrict__ aggb,
                  float* __restrict__ out) {
    __shared__ unsigned short As[3 * 128 * 32];  // [kh][m][k-chunks], 24576 B
    __shared__ unsigned short Bs[144 * 32];      // [l_local][k-chunks], 9216 B
    int bx = blockIdx.x;
    // XCD swizzle: all 16 blocks of one b land on the same XCD (bx % 8)
    int r8 = bx & 7, s = bx >> 3;
    int tile = s & 15, q = s >> 4;
    int b = r8 + 8 * q;
    int mt = tile & 1, nt = tile >> 1;
    int l0 = nt * 128, m0 = mt * 128;
    int t = threadIdx.x;
    int w = t >> 6, lane = t & 63;
    int ln = lane & 15, hi = lane >> 4;
    int wm = w & 1, wn = w >> 1;
    int jq = lane >> 2, jc = lane & 3;
    int gc = jc ^ ((jq >> 1) & 3);   // chunk-XOR swizzle on global source

    f32x4 acc[4][4];
    #pragma unroll
    for (int a = 0; a < 4; ++a)
        #pragma unroll
        for (int c = 0; c < 4; ++c) acc[a][c] = (f32x4){0.f, 0.f, 0.f, 0.f};

    const unsigned short* wb = wagg + (size_t)b * 3 * COUT * CIN;
    const unsigned short* xb = xbf + (size_t)b * LPAD * CIN;

    for (int it = 0; it < 8; ++it) {
        int i0 = it * 32;
        // A staging: 384 rows (3 kh x 128 m), 16 rows/instr, 6 instr/wave
        #pragma unroll
        for (int si = 0; si < 6; ++si) {
            int inst = w * 6 + si;
            int R = inst * 16 + jq;
            int kh = R >> 7, m = R & 127;
            const unsigned short* g =
                wb + ((size_t)(kh * COUT + m0 + m)) * CIN + i0 + gc * 8;
            load_lds16(g, &As[inst * 512]);
        }
        // B staging: 130 rows (l0 .. l0+129 in padded coords)
        for (int bi = w; bi < 9; bi += 4) {
            int r = bi * 16 + jq;
            if (r < 130) {
                const unsigned short* g = xb + (size_t)(l0 + r) * CIN + i0 + gc * 8;
                load_lds16(g, &Bs[bi * 512]);
            }
        }
        __syncthreads();
        #pragma unroll
        for (int kh = 0; kh < 3; ++kh) {
            bf16x8 af[4], bfr[4];
            #pragma unroll
            for (int mi = 0; mi < 4; ++mi) {
                int m = wm * 64 + mi * 16 + ln;
                af[mi] = *(const bf16x8*)&As[kh * 4096 + m * 32 + (hi ^ ((m >> 1) & 3)) * 8];
            }
            #pragma unroll
            for (int ni = 0; ni < 4; ++ni) {
                int r = wn * 64 + ni * 16 + ln + kh;
                bfr[ni] = *(const bf16x8*)&Bs[r * 32 + (hi ^ ((r >> 1) & 3)) * 8];
            }
            #pragma unroll
            for (int mi = 0; mi < 4; ++mi)
                #pragma unroll
                for (int ni = 0; ni < 4; ++ni)
                    acc[mi][ni] = __builtin_amdgcn_mfma_f32_16x16x32_bf16(
                        af[mi], bfr[ni], acc[mi][ni], 0, 0, 0);
        }
        __syncthreads();
    }

    // epilogue: C/D layout col=lane&15 (=l), row=(lane>>4)*4+reg (=o); add bias
    const float* abb = aggb + b * COUT;
    float* ob = out + (size_t)b * COUT * L_SZ;
    #pragma unroll
    for (int mi = 0; mi < 4; ++mi) {
        #pragma unroll
        for (int reg = 0; reg < 4; ++reg) {
            int o = m0 + wm * 64 + mi * 16 + hi * 4 + reg;
            float bv = abb[o];
            #pragma unroll
            for (int ni = 0; ni < 4; ++ni) {
                int l = l0 + wn * 64 + ni * 16 + ln;
                ob[(size_t)o * L_SZ + l] = acc[mi][ni][reg] + bv;
            }
        }
    }
}

extern "C" void kernel_launch(void* const* d_in, const int* in_sizes, int n_in,
                              void* d_out, int out_size, void* d_ws, size_t ws_size,
                              hipStream_t stream) {
    const float* x      = (const float*)d_in[0];
    const float* cond   = (const float*)d_in[1];
    const float* w1     = (const float*)d_in[2];
    const float* w2     = (const float*)d_in[3];
    const float* weight = (const float*)d_in[4];
    const float* bias   = (const float*)d_in[5];
    float* out = (float*)d_out;
    char* ws = (char*)d_ws;
    float* att_g  = (float*)(ws + OFF_ATT);
    float* aggb_g = (float*)(ws + OFF_AGGB);
    unsigned short* wagg = (unsigned short*)(ws + OFF_WAGG);
    unsigned short* xbf  = (unsigned short*)(ws + OFF_XBF);

    routing_kernel<<<64, 256, 0, stream>>>(cond, w1, w2, bias, att_g, aggb_g, xbf);
    xpose_kernel<<<dim3(16, 4, 64), 256, 0, stream>>>(x, xbf);
    wagg_kernel<<<dim3(256, 2), 256, 0, stream>>>(weight, att_g, wagg);
    dynconv_gemm<<<1024, 256, 0, stream>>>(wagg, xbf, aggb_g, out);
}